// Round 10
// baseline (133.214 us; speedup 1.0000x reference)
//
#include <hip/hip_runtime.h>
#include <math.h>

// ---------------- problem constants ----------------
#define NBLOCKS 2048
#define THREADS 256               // 4 waves/block
#define TILE 64
#define ITERS 8                   // one j-row (512 pos) per block
#define POS_PER_BLOCK 512

typedef __attribute__((ext_vector_type(8)))  short  short8;   // MFMA A/B frag
typedef __attribute__((ext_vector_type(16))) float  float16;  // 32x32 C/D frag

// gfx950 packed f32x2 -> bf16x2 (RNE), single VALU instruction
__device__ __forceinline__ unsigned cvt_pk(float lo, float hi) {
    unsigned r;
    asm("v_cvt_pk_bf16_f32 %0, %1, %2" : "=v"(r) : "v"(lo), "v"(hi));
    return r;
}

// Fully in-register pipeline: each wave owns 32 positions (pg) x 64 out-chs (ct2).
// Layer-1 (4 MFMAs) produces all 128 h1 chs for the wave's positions in C-layout;
// the k-permutation ch(16ks+s) = 16ks + (s&3) + 8*((s>>2)&1) + 4*(s>>3) makes the
// layer-2 B-frag for k-step ks EXACTLY the packed relu of octet (ks&1) of layer-1
// MFMA (ks>>1)'s C-regs (slot j = reg 8*(ks&1)+j; pairs pack adjacently).
// W2^T stationary (64 VGPRs); b2 via a 17th K-step (A=b2 hi/lo, B=1.0);
// layer-3 in-register (r9-verified mapping). No LDS except final 4-float partials;
// ONE barrier per block.
__global__ __launch_bounds__(256, 2)
void crpb_mfma9(const float* __restrict__ gq,   // (512,3)
                const float* __restrict__ gkv,  // (4,512,3)
                const float* __restrict__ W1,   // (3,128)
                const float* __restrict__ b1,   // (128,)
                const float* __restrict__ W2,   // (128,128)
                const float* __restrict__ b2,   // (128,)
                const float* __restrict__ W3,   // (128,4)
                const float* __restrict__ b3,   // (4,)
                float* __restrict__ out)        // (16,512,512)
{
    __shared__ __align__(16) float red[ITERS][2][4][64];   // 16 KB partials

    const int tid  = threadIdx.x;
    const int lane = tid & 63;
    const int w    = __builtin_amdgcn_readfirstlane(tid >> 6);  // 0..3
    const int l31  = lane & 31;
    const int lh   = lane >> 5;

    const int ct2 = w & 1;            // out-ch half: chs ct2*64 .. ct2*64+63
    const int pg  = w >> 1;           // pos-group (32 positions) within 64-tile
    const int pofs = pg * 32 + l31;   // lane's position within tile

    float16 z16;
    #pragma unroll
    for (int r = 0; r < 16; ++r) z16[r] = 0.0f;

    // ---- layer-1 A-frags for ALL 4 ch-tiles (16 VGPRs), W1 hi/lo + b1 folded ----
    short8 w1f[4];
    #pragma unroll
    for (int T = 0; T < 4; ++T) {
        const int ch = 32 * T + l31;
        const float w0 = W1[ch], w1v = W1[128 + ch], w2v = W1[256 + ch], b1v = b1[ch];
        const float w0h = __uint_as_float(cvt_pk(w0, w0) << 16);
        const float w1h = __uint_as_float(cvt_pk(w1v, w1v) << 16);
        const float w2h = __uint_as_float(cvt_pk(w2v, w2v) << 16);
        const float b1h = __uint_as_float(cvt_pk(b1v, b1v) << 16);
        const float w0l = w0 - w0h, w1l = w1v - w1h, w2l = w2v - w2h, b1l = b1v - b1h;
        unsigned d[4];
        if (lh == 0) {
            d[0] = cvt_pk(w0h, w0l);
            d[1] = cvt_pk(w0h, w1h);
            d[2] = cvt_pk(w1l, w1h);
            d[3] = cvt_pk(w2h, w2l);
        } else {
            d[0] = cvt_pk(w2h, b1h);
            d[1] = cvt_pk(b1l, 0.0f);
            d[2] = 0; d[3] = 0;
        }
        __builtin_memcpy(&w1f[T], d, 16);
    }

    // ---- W2^T stationary A-frags, k-permuted to match layer-1 C-octets (64 VGPRs) ----
    short8 a2fT[2][8];
    #pragma unroll
    for (int ot = 0; ot < 2; ++ot) {
        const int m = ct2 * 64 + ot * 32 + l31;     // out-ch row
        #pragma unroll
        for (int ks = 0; ks < 8; ++ks) {
            unsigned t0[4];
            #pragma unroll
            for (int t = 0; t < 4; ++t) {
                const int s  = 8 * lh + 2 * t;
                const int d0 = 16 * ks + (s & 3) + 8 * ((s >> 2) & 1) + 4 * (s >> 3);
                t0[t] = cvt_pk(W2[d0 * 128 + m], W2[(d0 + 1) * 128 + m]);
            }
            __builtin_memcpy(&a2fT[ot][ks], t0, 16);
        }
    }

    // ---- b2 K-step: A = (b2h, b2l) in slots k=0,1; B = 1.0 there (12 VGPRs) ----
    short8 a2b2[2];
    #pragma unroll
    for (int ot = 0; ot < 2; ++ot) {
        const int ch = ct2 * 64 + ot * 32 + l31;
        const float b2v = b2[ch];
        const float b2h = __uint_as_float(cvt_pk(b2v, b2v) << 16);
        const float b2l = b2v - b2h;
        unsigned d[4];
        d[0] = (lh == 0) ? cvt_pk(b2h, b2l) : 0u;
        d[1] = 0; d[2] = 0; d[3] = 0;
        __builtin_memcpy(&a2b2[ot], d, 16);
    }
    short8 bconst;
    {
        unsigned d[4];
        d[0] = (lh == 0) ? 0x3F803F80u : 0u;   // bf16(1.0) x2
        d[1] = 0; d[2] = 0; d[3] = 0;
        __builtin_memcpy(&bconst, d, 16);
    }

    // ---- W3 A-frags for in-register layer 3 (16 VGPRs), r9-verified mapping ----
    short8 w3a[2][2];
    #pragma unroll
    for (int ot = 0; ot < 2; ++ot) {
        #pragma unroll
        for (int m2 = 0; m2 < 2; ++m2) {
            unsigned tt[4];
            #pragma unroll
            for (int t = 0; t < 4; ++t) {
                const int chl = ((2 * t) & 3) + 8 * ((2 * t) >> 2) + 4 * lh + 16 * m2;
                const int ch0 = ct2 * 64 + ot * 32 + chl, ch1 = ch0 + 1;
                const float lo = (l31 < 4) ? W3[ch0 * 4 + l31] : 0.0f;
                const float hi = (l31 < 4) ? W3[ch1 * 4 + l31] : 0.0f;
                tt[t] = cvt_pk(lo, hi);
            }
            __builtin_memcpy(&w3a[ot][m2], tt, 16);
        }
    }

    // ---- block-constant indices: one j-row ----
    const int posblock = blockIdx.x * POS_PER_BLOCK;
    const int bb = posblock >> 18;
    const int i  = (posblock >> 9) & 511;
    const float q0 = gq[i * 3 + 0], q1 = gq[i * 3 + 1], q2 = gq[i * 3 + 2];
    const float* kvrow = gkv + (size_t)(bb << 9) * 3;

    // prefetch tile 0's kv
    const float* kp = kvrow + (size_t)pofs * 3;
    float kv0 = kp[0], kv1 = kp[1], kv2 = kp[2];

    for (int it = 0; it < ITERS; ++it) {
        // ---- features (per-lane, own position) + next-iter prefetch ----
        const float c0 = q0 - kv0, c1 = q1 - kv1, c2 = q2 - kv2;
        const float* kn = kvrow + (size_t)((((it + 1) & 7) << 6) + pofs) * 3;
        kv0 = kn[0]; kv1 = kn[1]; kv2 = kn[2];

        const float f0 = copysignf(__logf(1.0f + fabsf(c0)), c0);
        const float f1 = copysignf(__logf(1.0f + fabsf(c1)), c1);
        const float f2 = copysignf(__logf(1.0f + fabsf(c2)), c2);
        const unsigned u0 = cvt_pk(f0, f0), u2 = cvt_pk(f2, f2);
        const float f0h = __uint_as_float(u0 << 16);
        const float f1h = __uint_as_float(cvt_pk(f1, f1) << 16);
        const float f2h = __uint_as_float(u2 << 16);
        const float f0l = f0 - f0h, f1l = f1 - f1h, f2l = f2 - f2h;

        unsigned d[4];
        if (lh == 0) {
            d[0] = u0;                    // (f0h, f0h)
            d[1] = cvt_pk(f0l, f1);       // (f0l, f1h)
            d[2] = cvt_pk(f1, f1l);       // (f1h, f1l)
            d[3] = u2;                    // (f2h, f2h)
        } else {
            d[0] = cvt_pk(f2l, 1.0f);     // (f2l, 1.0) <- b1 pickup
            d[1] = cvt_pk(1.0f, 0.0f);
            d[2] = 0; d[3] = 0;
        }
        short8 bf; __builtin_memcpy(&bf, d, 16);

        // ---- acc init = b2 via constant-1.0 K-step ----
        float16 acc0 = __builtin_amdgcn_mfma_f32_32x32x16_bf16(a2b2[0], bconst, z16, 0, 0, 0);
        float16 acc1 = __builtin_amdgcn_mfma_f32_32x32x16_bf16(a2b2[1], bconst, z16, 0, 0, 0);

        // ---- staged layer-1 -> in-register B-frags -> layer-2 (no LDS!) ----
        #pragma unroll
        for (int T = 0; T < 4; ++T) {
            float16 c1r = __builtin_amdgcn_mfma_f32_32x32x16_bf16(w1f[T], bf, z16, 0, 0, 0);
            #pragma unroll
            for (int hi2 = 0; hi2 < 2; ++hi2) {        // ks = 2T + hi2
                unsigned pk[4];
                #pragma unroll
                for (int t = 0; t < 4; ++t)
                    pk[t] = cvt_pk(fmaxf(c1r[8 * hi2 + 2 * t], 0.f),
                                   fmaxf(c1r[8 * hi2 + 2 * t + 1], 0.f));
                short8 bf2; __builtin_memcpy(&bf2, pk, 16);
                acc0 = __builtin_amdgcn_mfma_f32_32x32x16_bf16(a2fT[0][2 * T + hi2], bf2, acc0, 0, 0, 0);
                acc1 = __builtin_amdgcn_mfma_f32_32x32x16_bf16(a2fT[1][2 * T + hi2], bf2, acc1, 0, 0, 0);
            }
        }

        // ---- layer-3 in-register (B-frag = packed relu(acc octets)) ----
        {
            unsigned pa0[4], pa1[4], pb0[4], pb1[4];
            #pragma unroll
            for (int t = 0; t < 4; ++t) {
                pa0[t] = cvt_pk(fmaxf(acc0[2 * t], 0.f),     fmaxf(acc0[2 * t + 1], 0.f));
                pa1[t] = cvt_pk(fmaxf(acc0[8 + 2 * t], 0.f), fmaxf(acc0[8 + 2 * t + 1], 0.f));
                pb0[t] = cvt_pk(fmaxf(acc1[2 * t], 0.f),     fmaxf(acc1[2 * t + 1], 0.f));
                pb1[t] = cvt_pk(fmaxf(acc1[8 + 2 * t], 0.f), fmaxf(acc1[8 + 2 * t + 1], 0.f));
            }
            short8 fa0, fa1, fb0, fb1;
            __builtin_memcpy(&fa0, pa0, 16); __builtin_memcpy(&fa1, pa1, 16);
            __builtin_memcpy(&fb0, pb0, 16); __builtin_memcpy(&fb1, pb1, 16);
            float16 p;
            p = __builtin_amdgcn_mfma_f32_32x32x16_bf16(w3a[0][0], fa0, z16, 0, 0, 0);
            p = __builtin_amdgcn_mfma_f32_32x32x16_bf16(w3a[0][1], fa1, p, 0, 0, 0);
            p = __builtin_amdgcn_mfma_f32_32x32x16_bf16(w3a[1][0], fb0, p, 0, 0, 0);
            p = __builtin_amdgcn_mfma_f32_32x32x16_bf16(w3a[1][1], fb1, p, 0, 0, 0);
            if (lh == 0) {
                #pragma unroll
                for (int o = 0; o < 4; ++o)
                    red[it][ct2][o][pofs] = p[o];
            }
        }
        // no barrier: zero cross-wave dependencies inside the loop
    }

    __syncthreads();   // the ONLY barrier: all red partials visible

    // ---- reduce + coalesced store: 8 tiles x (o = tid>>6, pos = tid&63) ----
    {
        const int o = tid >> 6, pos = tid & 63;
        const float b3v = b3[o];
        float* obase = out + ((size_t)((bb << 2) + o) << 18) + ((size_t)i << 9) + pos;
        #pragma unroll
        for (int it = 0; it < ITERS; ++it) {
            const float v = b3v + red[it][0][o][pos] + red[it][1][o][pos];
            obase[it * TILE] = v;
        }
    }
}

extern "C" void kernel_launch(void* const* d_in, const int* in_sizes, int n_in,
                              void* d_out, int out_size, void* d_ws, size_t ws_size,
                              hipStream_t stream) {
    const float* gq  = (const float*)d_in[0];
    const float* gkv = (const float*)d_in[1];
    const float* W1  = (const float*)d_in[2];
    const float* b1  = (const float*)d_in[3];
    const float* W2  = (const float*)d_in[4];
    const float* b2  = (const float*)d_in[5];
    const float* W3  = (const float*)d_in[6];
    const float* b3  = (const float*)d_in[7];
    float* out = (float*)d_out;

    crpb_mfma9<<<NBLOCKS, THREADS, 0, stream>>>(gq, gkv, W1, b1, W2, b2, W3, b3, out);
}